// Round 5
// baseline (173.409 us; speedup 1.0000x reference)
//
#include <hip/hip_runtime.h>
#include <math.h>

#define DD 32
#define MM 16
#define TROWH 80   // half elems per tbl row: t[32] | it[32] | cj[8] | pad[8]  (160B)

typedef _Float16 half8 __attribute__((ext_vector_type(8)));
typedef _Float16 half2t __attribute__((ext_vector_type(2)));

__device__ __forceinline__ void load8f4(const float* __restrict__ p, float* r) {
    const float4* q = (const float4*)p;
#pragma unroll
    for (int i = 0; i < 8; ++i) {
        float4 v = q[i];
        r[4*i+0] = v.x; r[4*i+1] = v.y; r[4*i+2] = v.z; r[4*i+3] = v.w;
    }
}

__device__ __forceinline__ float dot8(const float* a, const float* b) {
    float s0 = fmaf(a[0], b[0], fmaf(a[1], b[1], 0.f));
    float s1 = fmaf(a[2], b[2], fmaf(a[3], b[3], 0.f));
    float s2 = fmaf(a[4], b[4], fmaf(a[5], b[5], 0.f));
    float s3 = fmaf(a[6], b[6], fmaf(a[7], b[7], 0.f));
    return (s0 + s1) + (s2 + s3);
}

// user_table -> fp16 copy (rows 128B -> 64B). One thread per 8 elems.
__global__ void convert_user(const float* __restrict__ ut, _Float16* __restrict__ o, int n8) {
    int g = blockIdx.x * blockDim.x + threadIdx.x;
    if (g >= n8) return;
    const float4* p = (const float4*)ut + 2 * (size_t)g;
    float4 a = p[0], b = p[1];
    half8 h;
    h[0] = (_Float16)a.x; h[1] = (_Float16)a.y; h[2] = (_Float16)a.z; h[3] = (_Float16)a.w;
    h[4] = (_Float16)b.x; h[5] = (_Float16)b.y; h[6] = (_Float16)b.z; h[7] = (_Float16)b.w;
    *((half8*)o + g) = h;
}

// 4 threads per item; lane q computes t[q*8..q*8+7], copies it-slice, cj[2q..2q+1].
// All register-array indices compile-time (rule #20): the it-slice copy uses
// named float4 components, never it[runtime].
__global__ void precompute_item(const float* __restrict__ item_table,
                                const float* __restrict__ W_bil,
                                const float* __restrict__ W1,
                                _Float16* __restrict__ tbl, int NI) {
    int g = blockIdx.x * blockDim.x + threadIdx.x;
    int i = g >> 2, q = g & 3;
    if (i >= NI) return;
    int ko = q * 8;
    const float* row = item_table + (size_t)i * DD;
    float it[DD];
    load8f4(row, it);   // same addr across the quad -> broadcast
    _Float16* o = tbl + (size_t)i * TROWH;

    half8 th;
#pragma unroll
    for (int k = 0; k < 8; ++k) {
        const float* w = W_bil + (ko + k) * DD;
        float s0 = 0.f, s1 = 0.f, s2 = 0.f, s3 = 0.f;
#pragma unroll
        for (int e = 0; e < DD; e += 4) {
            s0 = fmaf(w[e+0], it[e+0], s0);
            s1 = fmaf(w[e+1], it[e+1], s1);
            s2 = fmaf(w[e+2], it[e+2], s2);
            s3 = fmaf(w[e+3], it[e+3], s3);
        }
        th[k] = (_Float16)((s0 + s1) + (s2 + s3));
    }
    *(half8*)(o + ko) = th;

    {   // it-slice copy via named vectors (L1-hot re-load, compile-time indices)
        const float4* ip = (const float4*)(row + ko);
        float4 a = ip[0], c = ip[1];
        half8 ih;
        ih[0] = (_Float16)a.x; ih[1] = (_Float16)a.y; ih[2] = (_Float16)a.z; ih[3] = (_Float16)a.w;
        ih[4] = (_Float16)c.x; ih[5] = (_Float16)c.y; ih[6] = (_Float16)c.z; ih[7] = (_Float16)c.w;
        *(half8*)(o + DD + ko) = ih;
    }

    int j0 = 2 * q;
    float c0 = 0.f, c1 = 0.f;
#pragma unroll
    for (int e = 0; e < DD; ++e) {
        c0 = fmaf(W1[j0 * 96 + 64 + e], it[e], c0);
        c1 = fmaf(W1[(j0 + 1) * 96 + 64 + e], it[e], c1);
    }
    half2t ch; ch[0] = (_Float16)c0; ch[1] = (_Float16)c1;
    *(half2t*)(o + 64 + 2 * q) = ch;
}

// Quad-cooperative main (round-4 structure) on fp16 gather tables, member-pair
// unrolled so two 16B row loads are in flight per iteration. All accumulation fp32.
__global__ __launch_bounds__(256)
void bilinear_main_h(const int* __restrict__ item_inputs,
                     const int* __restrict__ member_ids,
                     const unsigned char* __restrict__ member_mask,
                     const _Float16* __restrict__ ut_h,
                     const _Float16* __restrict__ tbl,
                     const float* __restrict__ b_bil,
                     const float* __restrict__ W1,
                     const float* __restrict__ b1v,
                     const float* __restrict__ W2,
                     const float* __restrict__ b2v,
                     float* __restrict__ out, int Btot) {
    int tid = blockIdx.x * blockDim.x + threadIdx.x;
    int b = tid >> 2;
    if (b >= Btot) return;
    int q = tid & 3;
    int ko = q * 8;

    int item = item_inputs[b];
    const uint4 mv = *(const uint4*)(member_mask + (size_t)b * MM);
    int len = __popc(mv.x & 0x01010101u) + __popc(mv.y & 0x01010101u) +
              __popc(mv.z & 0x01010101u) + __popc(mv.w & 0x01010101u);

    const _Float16* tb = tbl + (size_t)item * TROWH;
    half8 th = *(const half8*)(tb + ko);
    float t[8];
#pragma unroll
    for (int k = 0; k < 8; ++k) t[k] = (float)th[k];

    float bb = b_bil[0];
    float fin[8];
#pragma unroll
    for (int k = 0; k < 8; ++k) fin[k] = 0.f;

    const int* idp = member_ids + (size_t)b * MM;
    int m = 0;
    for (; m + 2 <= len; m += 2) {
        int ida = idp[m], idb = idp[m + 1];
        half8 ha = *(const half8*)(ut_h + (size_t)ida * DD + ko);
        half8 hb = *(const half8*)(ut_h + (size_t)idb * DD + ko);
        float ma[8], mc[8];
#pragma unroll
        for (int k = 0; k < 8; ++k) { ma[k] = (float)ha[k]; mc[k] = (float)hb[k]; }
        float sa = dot8(ma, t);
        float sb = dot8(mc, t);
        sa += __shfl_xor(sa, 1); sa += __shfl_xor(sa, 2);
        sb += __shfl_xor(sb, 1); sb += __shfl_xor(sb, 2);
        sa += bb; sb += bb;
#pragma unroll
        for (int k = 0; k < 8; ++k) fin[k] = fmaf(sb, mc[k], fmaf(sa, ma[k], fin[k]));
    }
    if (m < len) {
        int ida = idp[m];
        half8 ha = *(const half8*)(ut_h + (size_t)ida * DD + ko);
        float ma[8];
#pragma unroll
        for (int k = 0; k < 8; ++k) ma[k] = (float)ha[k];
        float sa = dot8(ma, t);
        sa += __shfl_xor(sa, 1); sa += __shfl_xor(sa, 2);
        sa += bb;
#pragma unroll
        for (int k = 0; k < 8; ++k) fin[k] = fmaf(sa, ma[k], fin[k]);
    }

    // it slice (fp16, same tbl row — already cached).
    half8 ih = *(const half8*)(tb + DD + ko);
    float it8[8];
#pragma unroll
    for (int k = 0; k < 8; ++k) it8[k] = (float)ih[k];

    float p8[8];
#pragma unroll
    for (int k = 0; k < 8; ++k) p8[k] = fin[k] * it8[k];

    // Per-lane partial of all 8 h_j over my 8 dims.
    float u[8];
#pragma unroll
    for (int j = 0; j < 8; ++j) {
        const float* wr = W1 + j * 96 + ko;
        float4 wa0 = *(const float4*)(wr);
        float4 wa1 = *(const float4*)(wr + 4);
        float4 wb0 = *(const float4*)(wr + 32);
        float4 wb1 = *(const float4*)(wr + 36);
        float x = 0.f, y = 0.f;
        x = fmaf(wa0.x, p8[0], x); y = fmaf(wb0.x, fin[0], y);
        x = fmaf(wa0.y, p8[1], x); y = fmaf(wb0.y, fin[1], y);
        x = fmaf(wa0.z, p8[2], x); y = fmaf(wb0.z, fin[2], y);
        x = fmaf(wa0.w, p8[3], x); y = fmaf(wb0.w, fin[3], y);
        x = fmaf(wa1.x, p8[4], x); y = fmaf(wb1.x, fin[4], y);
        x = fmaf(wa1.y, p8[5], x); y = fmaf(wb1.y, fin[5], y);
        x = fmaf(wa1.z, p8[6], x); y = fmaf(wb1.z, fin[6], y);
        x = fmaf(wa1.w, p8[7], x); y = fmaf(wb1.w, fin[7], y);
        u[j] = x + y;
    }
#pragma unroll
    for (int j = 0; j < 8; ++j) {
        u[j] += __shfl_xor(u[j], 1);
        u[j] += __shfl_xor(u[j], 2);
    }

    if (q == 0) {
        half8 ch = *(const half8*)(tb + 64);
        float z = b2v[0];
#pragma unroll
        for (int j = 0; j < 8; ++j) {
            float hv = u[j] + (float)ch[j] + b1v[j];
            hv = hv > 0.f ? hv : 0.f;
            z = fmaf(W2[j], hv, z);
        }
        __builtin_nontemporal_store(1.f / (1.f + __expf(-z)), out + b);
    }
}

// fp32 fallback (no workspace): round-4 quad kernel, tables computed inline.
__global__ __launch_bounds__(256)
void bilinear_main_f(const int* __restrict__ item_inputs,
                     const int* __restrict__ member_ids,
                     const unsigned char* __restrict__ member_mask,
                     const float* __restrict__ user_table,
                     const float* __restrict__ item_table,
                     const float* __restrict__ W_bil,
                     const float* __restrict__ b_bil,
                     const float* __restrict__ W1,
                     const float* __restrict__ b1v,
                     const float* __restrict__ W2,
                     const float* __restrict__ b2v,
                     float* __restrict__ out, int Btot) {
    int tid = blockIdx.x * blockDim.x + threadIdx.x;
    int b = tid >> 2;
    if (b >= Btot) return;
    int q = tid & 3;
    int ko = q * 8;

    int item = item_inputs[b];
    const uint4 mv = *(const uint4*)(member_mask + (size_t)b * MM);
    int len = __popc(mv.x & 0x01010101u) + __popc(mv.y & 0x01010101u) +
              __popc(mv.z & 0x01010101u) + __popc(mv.w & 0x01010101u);

    float itf[DD];
    load8f4(item_table + (size_t)item * DD, itf);
    float t[8];
#pragma unroll
    for (int k = 0; k < 8; ++k) {
        const float* w = W_bil + (ko + k) * DD;
        float s0 = 0.f, s1 = 0.f, s2 = 0.f, s3 = 0.f;
#pragma unroll
        for (int e = 0; e < DD; e += 4) {
            s0 = fmaf(w[e+0], itf[e+0], s0);
            s1 = fmaf(w[e+1], itf[e+1], s1);
            s2 = fmaf(w[e+2], itf[e+2], s2);
            s3 = fmaf(w[e+3], itf[e+3], s3);
        }
        t[k] = (s0 + s1) + (s2 + s3);
    }

    float bb = b_bil[0];
    float fin[8];
#pragma unroll
    for (int k = 0; k < 8; ++k) fin[k] = 0.f;

    const int* idp = member_ids + (size_t)b * MM;
    for (int m = 0; m < len; ++m) {
        int id = idp[m];
        const float4* up = (const float4*)(user_table + (size_t)id * DD + ko);
        float4 a = up[0], c = up[1];
        float me[8] = {a.x, a.y, a.z, a.w, c.x, c.y, c.z, c.w};
        float s = dot8(me, t);
        s += __shfl_xor(s, 1); s += __shfl_xor(s, 2);
        s += bb;
#pragma unroll
        for (int k = 0; k < 8; ++k) fin[k] = fmaf(s, me[k], fin[k]);
    }

    const float4* ip = (const float4*)(item_table + (size_t)item * DD + ko);
    float4 ia = ip[0], ic = ip[1];
    float it8[8] = {ia.x, ia.y, ia.z, ia.w, ic.x, ic.y, ic.z, ic.w};
    float p8[8];
#pragma unroll
    for (int k = 0; k < 8; ++k) p8[k] = fin[k] * it8[k];

    float u[8];
#pragma unroll
    for (int j = 0; j < 8; ++j) {
        const float* wr = W1 + j * 96 + ko;
        float4 wa0 = *(const float4*)(wr);
        float4 wa1 = *(const float4*)(wr + 4);
        float4 wb0 = *(const float4*)(wr + 32);
        float4 wb1 = *(const float4*)(wr + 36);
        float x = 0.f, y = 0.f;
        x = fmaf(wa0.x, p8[0], x); y = fmaf(wb0.x, fin[0], y);
        x = fmaf(wa0.y, p8[1], x); y = fmaf(wb0.y, fin[1], y);
        x = fmaf(wa0.z, p8[2], x); y = fmaf(wb0.z, fin[2], y);
        x = fmaf(wa0.w, p8[3], x); y = fmaf(wb0.w, fin[3], y);
        x = fmaf(wa1.x, p8[4], x); y = fmaf(wb1.x, fin[4], y);
        x = fmaf(wa1.y, p8[5], x); y = fmaf(wb1.y, fin[5], y);
        x = fmaf(wa1.z, p8[6], x); y = fmaf(wb1.z, fin[6], y);
        x = fmaf(wa1.w, p8[7], x); y = fmaf(wb1.w, fin[7], y);
        u[j] = x + y;
    }
#pragma unroll
    for (int j = 0; j < 8; ++j) {
        u[j] += __shfl_xor(u[j], 1);
        u[j] += __shfl_xor(u[j], 2);
    }

    if (q == 0) {
        float z = b2v[0];
#pragma unroll
        for (int j = 0; j < 8; ++j) {
            float cj = 0.f;
#pragma unroll
            for (int d = 0; d < DD; ++d) cj = fmaf(W1[j * 96 + 64 + d], itf[d], cj);
            float hv = u[j] + cj + b1v[j];
            hv = hv > 0.f ? hv : 0.f;
            z = fmaf(W2[j], hv, z);
        }
        __builtin_nontemporal_store(1.f / (1.f + __expf(-z)), out + b);
    }
}

extern "C" void kernel_launch(void* const* d_in, const int* in_sizes, int n_in,
                              void* d_out, int out_size, void* d_ws, size_t ws_size,
                              hipStream_t stream) {
    const int*           item_inputs = (const int*)d_in[0];
    const int*           member_ids  = (const int*)d_in[1];
    const unsigned char* member_mask = (const unsigned char*)d_in[2];
    const float*         user_table  = (const float*)d_in[3];
    const float*         item_table  = (const float*)d_in[4];
    const float*         W_bil       = (const float*)d_in[5];
    const float*         b_bil       = (const float*)d_in[6];
    const float*         W1          = (const float*)d_in[7];
    const float*         b1          = (const float*)d_in[8];
    const float*         W2          = (const float*)d_in[9];
    const float*         b2          = (const float*)d_in[10];
    float* out = (float*)d_out;

    int Btot = in_sizes[0];
    int NU   = in_sizes[3] / DD;
    int NI   = in_sizes[4] / DD;

    size_t tbl_bytes = (size_t)NI * TROWH * sizeof(_Float16);
    size_t ut_off    = (tbl_bytes + 255) & ~(size_t)255;
    size_t need      = ut_off + (size_t)NU * DD * sizeof(_Float16);

    int blk = 256;
    long long nthreads = (long long)Btot * 4;
    if (ws_size >= need) {
        _Float16* tbl  = (_Float16*)d_ws;
        _Float16* ut_h = (_Float16*)((char*)d_ws + ut_off);
        int n8 = NU * DD / 8;
        convert_user<<<(n8 + blk - 1) / blk, blk, 0, stream>>>(user_table, ut_h, n8);
        precompute_item<<<(NI * 4 + blk - 1) / blk, blk, 0, stream>>>(item_table, W_bil, W1, tbl, NI);
        bilinear_main_h<<<(int)((nthreads + blk - 1) / blk), blk, 0, stream>>>(
            item_inputs, member_ids, member_mask, ut_h, tbl,
            b_bil, W1, b1, W2, b2, out, Btot);
    } else {
        bilinear_main_f<<<(int)((nthreads + blk - 1) / blk), blk, 0, stream>>>(
            item_inputs, member_ids, member_mask, user_table, item_table,
            W_bil, b_bil, W1, b1, W2, b2, out, Btot);
    }
}